// Round 9
// baseline (37.484 us; speedup 1.0000x reference)
//
#include <hip/hip_runtime.h>

#define NB 16384
#define NN 31
#define NI 10
#define NOPS 4
#define NPASS 4
#define GB 16
#define TPB 512
#define NWAVES 8
#define NODES_PB (GB * NN)   // 496
#define MAXROWS 560          // >= worst-case padded rows (496 + 4*15 = 556)
#define MAXTILES 36
#define MAXT_PW 5            // ceil(35/8)
#define SROW 20              // floats per state row (80 B; cols 10..19 stay 0)
#define INVALID_NODE 0xFFFFu

typedef __attribute__((ext_vector_type(8))) short bf16x8_t;
typedef __attribute__((ext_vector_type(4))) float f32x4_t;

// ---- DPP sum over the 16 lanes of a DPP row ----
template <int CTRL>
__device__ __forceinline__ float dppf(float v) {
    return __int_as_float(__builtin_amdgcn_update_dpp(
        0, __float_as_int(v), CTRL, 0xF, 0xF, true));
}
__device__ __forceinline__ float rowsum16(float x) {
    x += dppf<0xB1>(x);     // quad_perm xor1
    x += dppf<0x4E>(x);     // quad_perm xor2
    x += dppf<0x124>(x);    // row_ror:4
    x += dppf<0x128>(x);    // row_ror:8
    return x;
}

__device__ __forceinline__ unsigned short f2bf(float f) {
    unsigned u = __float_as_uint(f);
    u += 0x7FFFu + ((u >> 16) & 1u);   // RNE
    return (unsigned short)(u >> 16);
}
// hardware packed f32->bf16 (RNE)
__device__ __forceinline__ unsigned cvtpk(float lo, float hi) {
    unsigned r;
    asm("v_cvt_pk_bf16_f32 %0, %1, %2" : "=v"(r) : "v"(lo), "v"(hi));
    return r;
}

// K-slot map (A and B agree; k = 32*s + 8*g + e; g = q on A, bq on B):
//   s in {0,1,2}: (i, j) = (4*s + g, e)   [i>=10 -> zero both sides]
//   s == 3: g=0:(e,8) g=1:(e,9) g=2,e<2:(8+e,8) g=3,e<2:(8+e,9), else zero
__global__ __launch_bounds__(TPB, 4) void listops_mfma(
    const int* __restrict__ cats, const int* __restrict__ ops,
    const int* __restrict__ lits, const int* __restrict__ left,
    const int* __restrict__ right, const float* __restrict__ tbl,
    float* __restrict__ out)
{
    __shared__ __align__(16) float st[NODES_PB][SROW];             // 38.8 KB, cols 10..19 == 0
    __shared__ __align__(16) unsigned short Bl[NOPS * 4 * 64 * 8]; // 16 KB B-fragments
    __shared__ unsigned short nodeOfRow[MAXROWS];                  // 1.1 KB
    __shared__ unsigned chLR[NODES_PB];                            // 2.0 KB
    __shared__ int cnt[NOPS], base_[NOPS];
    __shared__ int wbase[NWAVES][NOPS];
    __shared__ unsigned char tileOpSh[MAXTILES];
    __shared__ int nTilesSh;

    const int tid = threadIdx.x;
    const int wv  = tid >> 6;
    const int l   = tid & 63;
    const int q   = l >> 4;     // 0..3 : k-group
    const int c   = l & 15;     // 0..15: A-row (m) / C-col (n)
    const float initv = (c < NI) ? 0.0f : -50.0f;   // pad-col kill via acc init

    // -------- phase 0: LDS init + in-kernel B-fragment staging (2 rows/thread) --
    if (tid < NOPS) cnt[tid] = 0;
    nodeOfRow[tid] = (unsigned short)INVALID_NODE;
    if (tid < MAXROWS - TPB) nodeOfRow[TPB + tid] = (unsigned short)INVALID_NODE;
    #pragma unroll
    for (int rr = 0; rr < 2; ++rr) {
        const int fi   = tid + rr * TPB;   // 0..1023 fragment rows
        const int lane = fi & 63;
        const int step = (fi >> 6) & 3;
        const int op   = fi >> 8;
        const int bq = lane >> 4, bn = lane & 15;
        unsigned short v[8];
        #pragma unroll
        for (int e = 0; e < 8; ++e) {
            float val = 0.0f;
            if (bn < NI) {
                if (step < 2) {
                    val = tbl[((op * NI + 4 * step + bq) * NI + e) * NI + bn];
                } else if (step == 2) {
                    if (bq < 2) val = tbl[((op * NI + 8 + bq) * NI + e) * NI + bn];
                } else {
                    if (bq < 2)      val = tbl[((op * NI + e) * NI + 8 + bq) * NI + bn];
                    else if (e < 2)  val = tbl[((op * NI + 8 + e) * NI + 8 + (bq - 2)) * NI + bn];
                }
            }
            v[e] = f2bf(val);
        }
        uint4 pk;
        pk.x = (unsigned)v[0] | ((unsigned)v[1] << 16);
        pk.y = (unsigned)v[2] | ((unsigned)v[3] << 16);
        pk.z = (unsigned)v[4] | ((unsigned)v[5] << 16);
        pk.w = (unsigned)v[6] | ((unsigned)v[7] << 16);
        ((uint4*)&Bl[0])[fi] = pk;
    }
    __syncthreads();   // cnt zeroed before any atomicAdd

    // -------- phase 1: metadata, state init, ballot-based op ranking ------------
    bool isOp = false;
    int  myOp = 0;
    if (tid < NODES_PB) {
        int g   = blockIdx.x * NODES_PB + tid;   // coalesced
        int cat = cats[g];
        myOp    = min(max(ops[g], 0), NOPS - 1);
        int lit = min(max(lits[g], 0), NI - 1);
        int bl  = tid / NN;
        int cl  = bl * NN + min(max(left[g],  0), NN - 1);
        int cr  = bl * NN + min(max(right[g], 0), NN - 1);
        chLR[tid] = (unsigned)(cl * (SROW * 4)) | ((unsigned)(cr * (SROW * 4)) << 16);
        float4* rp = (float4*)&st[tid][0];
        rp[0] = make_float4(0.f, 0.f, 0.f, 0.f);
        rp[1] = make_float4(0.f, 0.f, 0.f, 0.f);
        rp[2] = make_float4(0.f, 0.f, 0.f, 0.f);
        rp[3] = make_float4(0.f, 0.f, 0.f, 0.f);
        rp[4] = make_float4(0.f, 0.f, 0.f, 0.f);
        if (cat == 0) {
            st[tid][lit] = 1.0f;
            if (tid == bl * NN) {                // literal root: output now
                float* o = out + (blockIdx.x * GB + bl) * NI;
                #pragma unroll
                for (int k = 0; k < NI; ++k) o[k] = (k == lit) ? 10.0f : 0.0f;
            }
        } else {
            isOp = true;
        }
    }
    // ballot ranking: 4 ballots/wave + 4 leader atomics
    int intra = 0;
    {
        const unsigned long long below = (1ull << l) - 1ull;
        #pragma unroll
        for (int o = 0; o < NOPS; ++o) {
            unsigned long long m = __ballot(isOp && (myOp == o));
            if (isOp && myOp == o) intra = __popcll(m & below);
            if (l == 0) wbase[wv][o] = atomicAdd(&cnt[o], __popcll(m));
        }
    }
    __syncthreads();

    if (tid == 0) {   // serial op-group layout (tiny)
        int rb = 0, t = 0;
        #pragma unroll
        for (int o = 0; o < NOPS; ++o) {
            base_[o] = rb;
            int nt = (cnt[o] + 15) >> 4;
            for (int i = 0; i < nt; ++i) tileOpSh[t++] = (unsigned char)o;
            rb += nt << 4;
        }
        nTilesSh = t;
    }
    __syncthreads();
    if (isOp) nodeOfRow[base_[myOp] + wbase[wv][myOp] + intra] = (unsigned short)tid;
    __syncthreads();

    const int nTiles = nTilesSh;

    // ---- hoist pass-invariant per-slot data ----
    unsigned slotLR[MAXT_PW];
    unsigned slotOps = 0;
    #pragma unroll
    for (int i = 0; i < MAXT_PW; ++i) {
        slotLR[i] = 0;
        int t = wv + NWAVES * i;
        if (t < nTiles) {
            int node = nodeOfRow[t * 16 + c];
            int nd0  = (node == (int)INVALID_NODE) ? 0 : node;  // pad rows read node 0 (finite, masked later)
            slotLR[i] = chLR[nd0];
            slotOps  |= ((unsigned)tileOpSh[t]) << (2 * i);
        }
    }

    const int q4    = q * 4;            // byte offset of L[q]
    const int psel  = (q < 2) ? 0 : 32; // patch lsel base offset
    const int rsoff = 32 + 4 * (q & 1); // rsel byte offset

    f32x4_t acc[MAXT_PW];

    for (int pass = 0; pass < NPASS; ++pass) {
        const bool last = (pass == NPASS - 1);

        // ============ phase A: per-lane A-frags in registers + 4 MFMA ============
        #pragma unroll
        for (int i = 0; i < MAXT_PW; ++i) {
            int t = wv + NWAVES * i;
            if (t < nTiles) {
                const char* sb = (const char*)&st[0][0];
                unsigned lrp = slotLR[i];
                const char* Lb = sb + (lrp & 0xFFFFu);
                const char* Rb = sb + (lrp >> 16);
                // L side: zero-padded rows make every q-variant a plain read
                float lq0 = *(const float*)(Lb + q4);            // L[q]
                float lq1 = *(const float*)(Lb + 16 + q4);       // L[4+q]
                float lq2 = *(const float*)(Lb + 32 + q4);       // L[8+q] (q>=2 -> 0 pad)
                float4 ls0 = *(const float4*)(Lb + psel);        // lsel[0..3]
                float4 ls1 = *(const float4*)(Lb + psel + 16);   // lsel[4..7]
                // R side
                float4 r0 = *(const float4*)Rb;
                float4 r1 = *(const float4*)(Rb + 16);
                float rsel = *(const float*)(Rb + rsoff);        // R[8] or R[9]

                float Re[8] = {r0.x, r0.y, r0.z, r0.w, r1.x, r1.y, r1.z, r1.w};
                float Ls[8] = {ls0.x, ls0.y, ls0.z, ls0.w, ls1.x, ls1.y, ls1.z, ls1.w};

                bf16x8_t av0, av1, av2, av3;
                unsigned* a0 = (unsigned*)&av0;
                unsigned* a1 = (unsigned*)&av1;
                unsigned* a2 = (unsigned*)&av2;
                unsigned* a3 = (unsigned*)&av3;
                #pragma unroll
                for (int d = 0; d < 4; ++d) {
                    a0[d] = cvtpk(lq0 * Re[2 * d], lq0 * Re[2 * d + 1]);
                    a1[d] = cvtpk(lq1 * Re[2 * d], lq1 * Re[2 * d + 1]);
                    a2[d] = cvtpk(lq2 * Re[2 * d], lq2 * Re[2 * d + 1]);
                    a3[d] = cvtpk(Ls[2 * d] * rsel, Ls[2 * d + 1] * rsel);
                }

                const char* Bp = (const char*)&Bl[0]
                               + ((slotOps >> (2 * i)) & 3u) * 4096u + l * 16;
                f32x4_t a = {initv, initv, initv, initv};
                a = __builtin_amdgcn_mfma_f32_16x16x32_bf16(av0, *(const bf16x8_t*)(Bp + 0 * 1024), a, 0, 0, 0);
                a = __builtin_amdgcn_mfma_f32_16x16x32_bf16(av1, *(const bf16x8_t*)(Bp + 1 * 1024), a, 0, 0, 0);
                a = __builtin_amdgcn_mfma_f32_16x16x32_bf16(av2, *(const bf16x8_t*)(Bp + 2 * 1024), a, 0, 0, 0);
                a = __builtin_amdgcn_mfma_f32_16x16x32_bf16(av3, *(const bf16x8_t*)(Bp + 3 * 1024), a, 0, 0, 0);
                acc[i] = a;
            }
        }

        if (!last) {
            __syncthreads();   // all state reads of this pass done
            // ===== phase B: softmax (pad cols carry -50 bias -> exp ~ 0) =====
            #pragma unroll
            for (int i = 0; i < MAXT_PW; ++i) {
                int t = wv + NWAVES * i;
                if (t < nTiles) {
                    f32x4_t a = acc[i];
                    ushort4 nds = *(const ushort4*)&nodeOfRow[t * 16 + 4 * q];
                    const unsigned short* np = (const unsigned short*)&nds;
                    #pragma unroll
                    for (int r = 0; r < 4; ++r) {
                        float ex = __expf(a[r]);
                        float sd = rowsum16(ex);
                        float pv = ex * __builtin_amdgcn_rcpf(sd);
                        unsigned short nd = np[r];
                        if (nd != (unsigned short)INVALID_NODE && c < NI)
                            st[nd][c] = pv;
                    }
                }
            }
            __syncthreads();   // new state visible
        } else {
            // ============== last pass: emit op-root raw logits ==============
            #pragma unroll
            for (int i = 0; i < MAXT_PW; ++i) {
                int t = wv + NWAVES * i;
                if (t < nTiles) {
                    f32x4_t a = acc[i];
                    ushort4 nds = *(const ushort4*)&nodeOfRow[t * 16 + 4 * q];
                    const unsigned short* np = (const unsigned short*)&nds;
                    #pragma unroll
                    for (int r = 0; r < 4; ++r) {
                        int nd = np[r];
                        if (nd != (int)INVALID_NODE && c < NI) {
                            int bl = nd / NN;
                            if (nd == bl * NN) {   // node 0 of its batch
                                out[(blockIdx.x * GB + bl) * NI + c] = a[r];
                            }
                        }
                    }
                }
            }
        }
    }
}

extern "C" void kernel_launch(void* const* d_in, const int* in_sizes, int n_in,
                              void* d_out, int out_size, void* d_ws, size_t ws_size,
                              hipStream_t stream) {
    const int*   cats     = (const int*)  d_in[0];
    const int*   ops      = (const int*)  d_in[1];
    const int*   lits     = (const int*)  d_in[2];
    const int*   left     = (const int*)  d_in[3];
    const int*   right    = (const int*)  d_in[4];
    // d_in[5] = mask (all true) — unused
    const float* op_table = (const float*)d_in[6];
    float*       out      = (float*)      d_out;

    hipLaunchKernelGGL(listops_mfma, dim3(NB / GB), dim3(TPB), 0, stream,
                       cats, ops, lits, left, right, op_table, out);
}